// Round 5
// baseline (393.075 us; speedup 1.0000x reference)
//
#include <hip/hip_runtime.h>
#include <hip/hip_bf16.h>
#include <cstdint>
#include <cstddef>

// B=2, L=2048, D_MODEL=1024, D_INNER=2048, D_STATE=16, D_CONV=4, DT_RANK=64
// M = B*L = 4096. All inputs/output fp32; internals bf16.
// R5: scan p1/p3: 64-step half-chunk staging (LDS 56->40KB, 2->4 blocks/CU),
//     exp2f with pre-scaled A (kills 4 v_mul/step), silu+z moved out of the
//     t-loop into the coalesced store stage; fused cvt kernel.

typedef __bf16 bf16x8 __attribute__((ext_vector_type(8)));
typedef __bf16 bf16x4 __attribute__((ext_vector_type(4)));
typedef float f32x4 __attribute__((ext_vector_type(4)));
typedef unsigned int u32x4 __attribute__((ext_vector_type(4)));

#define LOG2E 1.44269504088896f

__device__ __forceinline__ bf16x8 cvt8(const float* __restrict__ p) {
    f32x4 a = *(const f32x4*)p;
    f32x4 b = *(const f32x4*)(p + 4);
    bf16x8 o;
    o[0] = (__bf16)a[0]; o[1] = (__bf16)a[1]; o[2] = (__bf16)a[2]; o[3] = (__bf16)a[3];
    o[4] = (__bf16)b[0]; o[5] = (__bf16)b[1]; o[6] = (__bf16)b[2]; o[7] = (__bf16)b[3];
    return o;
}

__device__ __forceinline__ void gll16(const __bf16* g, __bf16* l) {
    __builtin_amdgcn_global_load_lds(
        (const __attribute__((address_space(1))) void*)g,
        (__attribute__((address_space(3))) void*)l, 16, 0, 0);
}

__device__ __forceinline__ uint32_t packbf(__bf16 lo, __bf16 hi) {
    uint16_t a = __builtin_bit_cast(uint16_t, lo);
    uint16_t b = __builtin_bit_cast(uint16_t, hi);
    return (uint32_t)a | ((uint32_t)b << 16);
}
__device__ __forceinline__ float lo2f(uint32_t u) { return __builtin_bit_cast(float, u << 16); }
__device__ __forceinline__ float hi2f(uint32_t u) { return __builtin_bit_cast(float, u & 0xffff0000u); }

// quad_perm DPP add: 0xB1 = xor1, 0x4E = xor2
template<int CTRL>
__device__ __forceinline__ float qp_add(float v) {
    int r = __builtin_amdgcn_update_dpp(0, __builtin_bit_cast(int, v), CTRL, 0xF, 0xF, true);
    return v + __builtin_bit_cast(float, r);
}

// ---------------------------------------------------------------------------
// fused f32->bf16 convert of u, W_in, W_out, W_x, W_dt (8 elems/thread)
// ranges in 8-elem units: u 524288 | W_in 524288 | W_out 262144 | W_x 24576 | W_dt 16384
// ---------------------------------------------------------------------------
__global__ void cvt_all_kernel(const float* __restrict__ u,   __bf16* __restrict__ ub,
                               const float* __restrict__ wi,  __bf16* __restrict__ wib,
                               const float* __restrict__ wo,  __bf16* __restrict__ wob,
                               const float* __restrict__ wx,  __bf16* __restrict__ wxb,
                               const float* __restrict__ wdt, __bf16* __restrict__ wdtb) {
    int i = blockIdx.x * 256 + threadIdx.x;      // 0 .. 1351679
    const float* s; __bf16* d; int off;
    if (i < 524288)                { s = u;   d = ub;   off = i; }
    else if (i < 1048576)          { s = wi;  d = wib;  off = i - 524288; }
    else if (i < 1310720)          { s = wo;  d = wob;  off = i - 1048576; }
    else if (i < 1335296)          { s = wx;  d = wxb;  off = i - 1310720; }
    else                           { s = wdt; d = wdtb; off = i - 1335296; }
    *(bf16x8*)(d + (size_t)off * 8) = cvt8(s + (size_t)off * 8);
}

// ---------------------------------------------------------------------------
// m97-style GEMM: C[M][ldc] = A[M][K] @ B[N][K]^T, bf16 in, 128x128 tile.
// ---------------------------------------------------------------------------
#define GEMM_BODY(EPILOG)                                                       \
    __shared__ __bf16 As[128][32];                                              \
    __shared__ __bf16 Bs[128][32];                                              \
    const int tid = threadIdx.x, lane = tid & 63, wave = tid >> 6;              \
    const int m0 = blockIdx.x * 128, n0 = blockIdx.y * 128;                     \
    const int wm = (wave >> 1) * 64, wn = (wave & 1) * 64;                      \
    const int mrow = lane & 15, kq = (lane >> 4) * 8;                           \
    const int sr = wave * 32 + (lane >> 2);                                     \
    const int sk = (lane & 3) * 8;                                              \
    const __bf16* Ag0 = A + (size_t)(m0 + sr) * K + sk;                         \
    const __bf16* Ag1 = Ag0 + (size_t)16 * K;                                   \
    const __bf16* Bg0 = Bw + (size_t)(n0 + sr) * K + sk;                        \
    const __bf16* Bg1 = Bg0 + (size_t)16 * K;                                   \
    __bf16* La0 = &As[wave * 32][0];                                            \
    __bf16* La1 = &As[wave * 32 + 16][0];                                       \
    __bf16* Lb0 = &Bs[wave * 32][0];                                            \
    __bf16* Lb1 = &Bs[wave * 32 + 16][0];                                       \
    f32x4 acc[4][4] = {};                                                       \
    for (int k0 = 0; k0 < K; k0 += 32) {                                        \
        gll16(Ag0 + k0, La0);                                                   \
        gll16(Ag1 + k0, La1);                                                   \
        gll16(Bg0 + k0, Lb0);                                                   \
        gll16(Bg1 + k0, Lb1);                                                   \
        __syncthreads();                                                        \
        bf16x8 af[4], bfr[4];                                                   \
        _Pragma("unroll")                                                       \
        for (int i = 0; i < 4; ++i) af[i]  = *(const bf16x8*)&As[wm + i * 16 + mrow][kq]; \
        _Pragma("unroll")                                                       \
        for (int j = 0; j < 4; ++j) bfr[j] = *(const bf16x8*)&Bs[wn + j * 16 + mrow][kq]; \
        _Pragma("unroll")                                                       \
        for (int i = 0; i < 4; ++i)                                             \
            _Pragma("unroll")                                                   \
            for (int j = 0; j < 4; ++j)                                         \
                acc[i][j] = __builtin_amdgcn_mfma_f32_16x16x32_bf16(af[i], bfr[j], acc[i][j], 0, 0, 0); \
        __syncthreads();                                                        \
    }                                                                           \
    const int col = lane & 15;                                                  \
    const int rb = (lane >> 4) * 4;                                             \
    _Pragma("unroll")                                                           \
    for (int i = 0; i < 4; ++i)                                                 \
        _Pragma("unroll")                                                       \
        for (int j = 0; j < 4; ++j)                                             \
            _Pragma("unroll")                                                   \
            for (int r = 0; r < 4; ++r)                                         \
                EPILOG;

__global__ __launch_bounds__(256, 2) void gemm_async_bf(const __bf16* __restrict__ A,
                                                        const __bf16* __restrict__ Bw,
                                                        __bf16* __restrict__ C,
                                                        int K, int ldc) {
    GEMM_BODY(C[(size_t)(m0 + wm + i * 16 + rb + r) * ldc + n0 + wn + j * 16 + col] = (__bf16)acc[i][j][r])
}

__global__ __launch_bounds__(256, 2) void gemm_async_f32(const __bf16* __restrict__ A,
                                                         const __bf16* __restrict__ Bw,
                                                         float* __restrict__ C,
                                                         int K, int ldc) {
    GEMM_BODY(C[(size_t)(m0 + wm + i * 16 + rb + r) * ldc + n0 + wn + j * 16 + col] = acc[i][j][r])
}

// ---------------------------------------------------------------------------
// Causal depthwise conv (K=4) + SiLU
// ---------------------------------------------------------------------------
__global__ void conv_silu_kernel(const __bf16* __restrict__ xz,
                                 const float* __restrict__ cw,
                                 const float* __restrict__ cb,
                                 __bf16* __restrict__ x) {
    int tid = threadIdx.x;
    int r = blockIdx.x;
    int l = r & 2047;
    int d = tid * 8;

    float acc[8];
#pragma unroll
    for (int i = 0; i < 8; ++i) acc[i] = cb[d + i];

#pragma unroll
    for (int dlt = 0; dlt < 4; ++dlt) {
        if (l - dlt < 0) break;
        bf16x8 v = *(const bf16x8*)(xz + (size_t)(r - dlt) * 4096 + d);
#pragma unroll
        for (int i = 0; i < 8; ++i)
            acc[i] += (float)v[i] * cw[(d + i) * 4 + 3 - dlt];
    }
    bf16x8 o;
#pragma unroll
    for (int i = 0; i < 8; ++i) {
        float s = acc[i];
        s = s / (1.f + __expf(-s));
        o[i] = (__bf16)s;
    }
    *(bf16x8*)(x + (size_t)r * 2048 + d) = o;
}

// ---------------------------------------------------------------------------
// gemm_xp split-K: P[ks][4096][96] = x[:, ks*256:(ks+1)*256] @ Wx^T
// ---------------------------------------------------------------------------
__global__ __launch_bounds__(256, 2) void gemm_xp_split(const __bf16* __restrict__ A,
                                                        const __bf16* __restrict__ Bw,
                                                        float* __restrict__ P) {
    __shared__ __bf16 As[64][64];
    __shared__ __bf16 Bs[96][64];
    const int tid = threadIdx.x;
    const int lane = tid & 63;
    const int wave = tid >> 6;
    const int m0 = blockIdx.x * 64;
    const int kb = blockIdx.y * 256;
    const int mrow = lane & 15;
    const int kq = (lane >> 4) * 8;

    f32x4 acc[6] = {};

    for (int k0 = kb; k0 < kb + 256; k0 += 64) {
#pragma unroll
        for (int r = 0; r < 2; ++r) {
            int e = r * 256 + tid;
            int row = e >> 3, kc = e & 7;
            *(bf16x8*)&As[row][kc * 8] =
                *(const bf16x8*)(A + (size_t)(m0 + row) * 2048 + k0 + kc * 8);
        }
#pragma unroll
        for (int r = 0; r < 3; ++r) {
            int e = r * 256 + tid;
            int row = e >> 3, kc = e & 7;
            *(bf16x8*)&Bs[row][kc * 8] =
                *(const bf16x8*)(Bw + (size_t)row * 2048 + k0 + kc * 8);
        }
        __syncthreads();
#pragma unroll
        for (int kc = 0; kc < 2; ++kc) {
            bf16x8 af = *(const bf16x8*)&As[wave * 16 + mrow][kc * 32 + kq];
#pragma unroll
            for (int j = 0; j < 6; ++j) {
                bf16x8 bfr = *(const bf16x8*)&Bs[j * 16 + mrow][kc * 32 + kq];
                acc[j] = __builtin_amdgcn_mfma_f32_16x16x32_bf16(af, bfr, acc[j], 0, 0, 0);
            }
        }
        __syncthreads();
    }
    const int col = lane & 15;
    const int rb = (lane >> 4) * 4;
    float* Pb = P + (size_t)blockIdx.y * 4096 * 96;
#pragma unroll
    for (int j = 0; j < 6; ++j)
#pragma unroll
        for (int r = 0; r < 4; ++r)
            Pb[(size_t)(m0 + wave * 16 + rb + r) * 96 + j * 16 + col] = acc[j][r];
}

__global__ void xp_reduce(const float* __restrict__ P, __bf16* __restrict__ xp) {
    int m = blockIdx.x, c = threadIdx.x;
    if (c < 96) {
        float s = 0.f;
#pragma unroll
        for (int k = 0; k < 8; ++k) s += P[(size_t)k * 4096 * 96 + (size_t)m * 96 + c];
        xp[(size_t)m * 96 + c] = (__bf16)s;
    }
}

// ---------------------------------------------------------------------------
// dt = softplus(x_p[:, :64] @ W_dt^T + b_dt) -> bf16 into xz[:, :2048]
// ---------------------------------------------------------------------------
__global__ __launch_bounds__(256, 2) void gemm_dt(const __bf16* __restrict__ xp,
                                                  const __bf16* __restrict__ Wdt,
                                                  const float* __restrict__ bdt,
                                                  __bf16* __restrict__ dt) {
    const int tid = threadIdx.x;
    const int lane = tid & 63;
    const int wave = tid >> 6;
    const int m0 = blockIdx.x * 128 + (wave >> 1) * 64;
    const int n0 = blockIdx.y * 128 + (wave & 1) * 64;
    const int mrow = lane & 15;
    const int kq = (lane >> 4) * 8;

    f32x4 acc[4][4] = {};
#pragma unroll
    for (int kc = 0; kc < 2; ++kc) {
        bf16x8 af[4], bfr[4];
#pragma unroll
        for (int i = 0; i < 4; ++i)
            af[i] = *(const bf16x8*)(xp + (size_t)(m0 + i * 16 + mrow) * 96 + kc * 32 + kq);
#pragma unroll
        for (int j = 0; j < 4; ++j)
            bfr[j] = *(const bf16x8*)(Wdt + (size_t)(n0 + j * 16 + mrow) * 64 + kc * 32 + kq);
#pragma unroll
        for (int i = 0; i < 4; ++i)
#pragma unroll
            for (int j = 0; j < 4; ++j)
                acc[i][j] = __builtin_amdgcn_mfma_f32_16x16x32_bf16(af[i], bfr[j], acc[i][j], 0, 0, 0);
    }
    const int col = lane & 15;
    const int rb = (lane >> 4) * 4;
#pragma unroll
    for (int i = 0; i < 4; ++i)
#pragma unroll
        for (int j = 0; j < 4; ++j) {
            int cc = n0 + j * 16 + col;
            float bias = bdt[cc];
#pragma unroll
            for (int r = 0; r < 4; ++r) {
                float v = acc[i][j][r] + bias;
                float sp = (v > 20.f) ? v : log1pf(__expf(v));
                dt[(size_t)(m0 + i * 16 + rb + r) * 4096 + cc] = (__bf16)sp;
            }
        }
}

// ---------------------------------------------------------------------------
// Chunked scan, 16 chunks x 128 steps, staged in 64-step halves.
// Block = 64 d x 4 waves; wave = 16 d x 4 n-groups, 4 states/thread.
// Grid = 2b x 16c x 32 = 1024 blocks.
// ---------------------------------------------------------------------------
__global__ __launch_bounds__(256, 4) void scan_p1(const __bf16* __restrict__ xz,
                                                  const __bf16* __restrict__ xq,
                                                  const __bf16* __restrict__ xp,
                                                  const float* __restrict__ A_log,
                                                  float* __restrict__ h_end,
                                                  float* __restrict__ dtsum) {
    __shared__ uint32_t s_dtx[64][64];    // (x<<16)|dt, half-chunk
    __shared__ __bf16 s_B[128][16];
    const int tid = threadIdx.x;
    const int bi = blockIdx.x;
    const int b = bi >> 9, c = (bi >> 5) & 15, d0 = (bi & 31) * 64;
    const int row0 = b * 2048 + c * 128;

    const int lane = tid & 63, wave = tid >> 6;
    const int dcol = wave * 16 + (lane >> 2);
    const int d = d0 + dcol;
    const int ng = lane & 3;
    f32x4 Al = *(const f32x4*)(A_log + (size_t)d * 16 + ng * 4);
    float Adn2[4];
#pragma unroll
    for (int j = 0; j < 4; ++j) Adn2[j] = -__expf(Al[j]) * LOG2E;

    // stage B for all 128 t
#pragma unroll
    for (int i = 0; i < 2; ++i) {
        int w = i * 256 + tid;
        int t = w >> 2, g = (w & 3) * 4;
        *(bf16x4*)&s_B[t][g] = *(const bf16x4*)(xp + (size_t)(row0 + t) * 96 + 64 + g);
    }

    float h[4] = {0.f, 0.f, 0.f, 0.f};
    float ds = 0.f;
    for (int ch = 0; ch < 2; ++ch) {
        if (ch) __syncthreads();
#pragma unroll
        for (int i = 0; i < 4; ++i) {
            int w = i * 256 + tid;
            int t = w >> 4, g = (w & 15) * 4;
            size_t r = (size_t)(row0 + ch * 64 + t);
            bf16x4 dt4 = *(const bf16x4*)(xz + r * 4096 + d0 + g);
            bf16x4 x4  = *(const bf16x4*)(xq + r * 2048 + d0 + g);
            u32x4 o;
#pragma unroll
            for (int k = 0; k < 4; ++k) o[k] = packbf(dt4[k], x4[k]);
            *(u32x4*)&s_dtx[t][g] = o;
        }
        __syncthreads();
#pragma unroll 8
        for (int t = 0; t < 64; ++t) {
            uint32_t u = s_dtx[t][dcol];
            float dt = lo2f(u), x = hi2f(u);
            bf16x4 B4 = *(const bf16x4*)&s_B[ch * 64 + t][ng * 4];
            float p = dt * x;
#pragma unroll
            for (int j = 0; j < 4; ++j) {
                float dA = exp2f(dt * Adn2[j]);
                h[j] = fmaf(dA, h[j], p * (float)B4[j]);
            }
            ds += dt;
        }
    }
    size_t base = (size_t)(b * 16 + c) * 2048 + d;
    f32x4 hv = {h[0], h[1], h[2], h[3]};
    *(f32x4*)(h_end + base * 16 + ng * 4) = hv;
    if (ng == 0) dtsum[base] = ds;
}

// Phase 2: prefix over 16 chunks per (b,d,n).
__global__ __launch_bounds__(256) void scan_p2(const float* __restrict__ A_log,
                                               const float* __restrict__ dtsum,
                                               const float* __restrict__ h_end,
                                               float* __restrict__ h_in) {
    int idx = blockIdx.x * 256 + threadIdx.x;
    int b = idx >> 15, rem = idx & 32767;
    int d = rem >> 4;
    float Adn = -__expf(A_log[rem]);
    float h = 0.f;
#pragma unroll
    for (int c = 0; c < 16; ++c) {
        size_t base = ((size_t)(b * 16 + c) << 15) + rem;
        h_in[base] = h;
        float P = __expf(Adn * dtsum[((size_t)(b * 16 + c) << 11) + d]);
        h = fmaf(P, h, h_end[base]);
    }
}

// Phase 3: rerun from h_in; inner loop emits raw y' = C.h + D*x to LDS;
// store stage applies y = y' * silu(z) with coalesced z rows.
__global__ __launch_bounds__(256, 4) void scan_p3(const __bf16* __restrict__ xz,
                                                  __bf16* __restrict__ xq,
                                                  const __bf16* __restrict__ xp,
                                                  const float* __restrict__ A_log,
                                                  const float* __restrict__ Dp,
                                                  const float* __restrict__ h_in) {
    __shared__ uint32_t s_dtx[64][64];    // (x<<16)|dt, half-chunk
    __shared__ uint32_t s_BC[128][16];    // (C<<16)|B
    __shared__ __bf16 s_y[128][64];       // raw y' = C.h + D*x
    const int tid = threadIdx.x;
    const int bi = blockIdx.x;
    const int b = bi >> 9, c = (bi >> 5) & 15, d0 = (bi & 31) * 64;
    const int row0 = b * 2048 + c * 128;

    const int lane = tid & 63, wave = tid >> 6;
    const int dcol = wave * 16 + (lane >> 2);
    const int d = d0 + dcol;
    const int ng = lane & 3;
    f32x4 Al = *(const f32x4*)(A_log + (size_t)d * 16 + ng * 4);
    float Adn2[4];
#pragma unroll
    for (int j = 0; j < 4; ++j) Adn2[j] = -__expf(Al[j]) * LOG2E;
    const float Dd = Dp[d];
    f32x4 h = *(const f32x4*)(h_in + ((size_t)(b * 16 + c) * 2048 + d) * 16 + ng * 4);

    // stage B,C for all 128 t
#pragma unroll
    for (int i = 0; i < 2; ++i) {
        int w = i * 256 + tid;
        int t = w >> 2, g = (w & 3) * 4;
        bf16x4 B4 = *(const bf16x4*)(xp + (size_t)(row0 + t) * 96 + 64 + g);
        bf16x4 C4 = *(const bf16x4*)(xp + (size_t)(row0 + t) * 96 + 80 + g);
        u32x4 o;
#pragma unroll
        for (int k = 0; k < 4; ++k) o[k] = packbf(B4[k], C4[k]);
        *(u32x4*)&s_BC[t][g] = o;
    }

    for (int ch = 0; ch < 2; ++ch) {
        if (ch) __syncthreads();
#pragma unroll
        for (int i = 0; i < 4; ++i) {
            int w = i * 256 + tid;
            int t = w >> 4, g = (w & 15) * 4;
            size_t r = (size_t)(row0 + ch * 64 + t);
            bf16x4 dt4 = *(const bf16x4*)(xz + r * 4096 + d0 + g);
            bf16x4 x4  = *(const bf16x4*)(xq + r * 2048 + d0 + g);
            u32x4 o;
#pragma unroll
            for (int k = 0; k < 4; ++k) o[k] = packbf(dt4[k], x4[k]);
            *(u32x4*)&s_dtx[t][g] = o;
        }
        __syncthreads();
#pragma unroll 8
        for (int t = 0; t < 64; ++t) {
            uint32_t u = s_dtx[t][dcol];
            float dt = lo2f(u), x = hi2f(u);
            u32x4 bc = *(const u32x4*)&s_BC[ch * 64 + t][ng * 4];
            float p = dt * x;
            float cs;
#pragma unroll
            for (int j = 0; j < 4; ++j) {
                float Bv = lo2f(bc[j]), Cv = hi2f(bc[j]);
                float dA = exp2f(dt * Adn2[j]);
                h[j] = fmaf(dA, h[j], p * Bv);
                cs = (j == 0) ? h[0] * Cv : fmaf(h[j], Cv, cs);
            }
            cs = qp_add<0xB1>(cs);
            cs = qp_add<0x4E>(cs);
            if (ng == 0) s_y[ch * 64 + t][dcol] = (__bf16)fmaf(Dd, x, cs);
        }
    }
    __syncthreads();
    // store stage: y = y' * silu(z), z read coalesced from xz rows
#pragma unroll
    for (int i = 0; i < 4; ++i) {
        int w = i * 256 + tid;
        int t = w >> 3, g = (w & 7) * 8;
        bf16x8 z8 = *(const bf16x8*)(xz + (size_t)(row0 + t) * 4096 + 2048 + d0 + g);
        bf16x8 y8 = *(bf16x8*)&s_y[t][g];
        bf16x8 o;
#pragma unroll
        for (int k = 0; k < 8; ++k) {
            float zv = (float)z8[k];
            float yv = (float)y8[k] * (zv / (1.f + __expf(-zv)));
            o[k] = (__bf16)yv;
        }
        *(bf16x8*)(xq + (size_t)(row0 + t) * 2048 + d0 + g) = o;
    }
}

// ---------------------------------------------------------------------------
extern "C" void kernel_launch(void* const* d_in, const int* in_sizes, int n_in,
                              void* d_out, int out_size, void* d_ws, size_t ws_size,
                              hipStream_t stream) {
    const float* u      = (const float*)d_in[0];
    const float* W_in   = (const float*)d_in[1];
    const float* W_out  = (const float*)d_in[2];
    const float* conv_w = (const float*)d_in[3];
    const float* conv_b = (const float*)d_in[4];
    const float* W_x    = (const float*)d_in[5];
    const float* W_dt   = (const float*)d_in[6];
    const float* b_dt   = (const float*)d_in[7];
    const float* A_log  = (const float*)d_in[8];
    const float* D_p    = (const float*)d_in[9];
    float* out = (float*)d_out;

    // ws (bf16), ~61.4 MB:
    __bf16* xz   = (__bf16*)d_ws;                   // [4096][4096]: x_in->dt | z
    __bf16* xq   = xz  + (size_t)4096 * 4096;       // [4096][2048]: x -> y
    __bf16* xp   = xq  + (size_t)4096 * 2048;       // [4096][96]
    __bf16* Wib  = xp  + (size_t)4096 * 96;         // W_in  bf16 [4096][1024]
    __bf16* Wob  = Wib + (size_t)4096 * 1024;       // W_out bf16 [1024][2048]
    __bf16* Wxb  = Wob + (size_t)1024 * 2048;       // W_x   bf16 [96][2048]
    __bf16* Wdtb = Wxb + (size_t)96 * 2048;         // W_dt  bf16 [2048][64]

    // d_out doubles as scratch:
    __bf16* ub    = (__bf16*)d_out;                 // u bf16 (dead after gemm1)
    float* xpart  = (float*)d_out;                  // [8][4096][96] partials
    float* dtsum  = (float*)d_out;                  // 256 KB (after xpart dead)
    float* h_end  = (float*)d_out + 2097152;        // 4 MB @ 8MB
    float* h_in   = (float*)d_out + 3145728;        // 4 MB @ 12MB

    cvt_all_kernel<<<5280, 256, 0, stream>>>(u, ub, W_in, Wib, W_out, Wob,
                                             W_x, Wxb, W_dt, Wdtb);

    // 1. xz = ub @ Wib^T  (M=4096,N=4096,K=1024)
    gemm_async_bf<<<dim3(32, 32), 256, 0, stream>>>(ub, Wib, xz, 1024, 4096);
    // 2. x = silu(conv(x_in))
    conv_silu_kernel<<<4096, 256, 0, stream>>>(xz, conv_w, conv_b, xq);
    // 3. x_p split-K + reduce
    gemm_xp_split<<<dim3(64, 8), 256, 0, stream>>>(xq, Wxb, xpart);
    xp_reduce<<<4096, 128, 0, stream>>>(xpart, xp);
    // 4. dt -> xz[:, :2048]
    gemm_dt<<<dim3(32, 16), 256, 0, stream>>>(xp, Wdtb, b_dt, xz);
    // 5. chunked scan
    scan_p1<<<1024, 256, 0, stream>>>(xz, xq, xp, A_log, h_end, dtsum);
    scan_p2<<<256, 256, 0, stream>>>(A_log, dtsum, h_end, h_in);
    scan_p3<<<1024, 256, 0, stream>>>(xz, xq, xp, A_log, D_p, h_in);
    // 6. out = y @ Wob^T  (M=4096,N=1024,K=2048)
    gemm_async_f32<<<dim3(32, 8), 256, 0, stream>>>(xq, Wob, out, 2048, 1024);
}

// Round 6
// 381.426 us; speedup vs baseline: 1.0305x; 1.0305x over previous
//
#include <hip/hip_runtime.h>
#include <hip/hip_bf16.h>
#include <cstdint>
#include <cstddef>

// B=2, L=2048, D_MODEL=1024, D_INNER=2048, D_STATE=16, D_CONV=4, DT_RANK=64
// M = B*L = 4096. All inputs/output fp32; internals bf16.
// R6: 32x64-step scan chunks (p1 8 blk/CU, p3 5 blk/CU, 2 barriers);
//     gemm6 split-K x2 into xz scratch + add-reduce; launch_bounds(256,3)
//     on big GEMMs for 3 blocks/CU residency.

typedef __bf16 bf16x8 __attribute__((ext_vector_type(8)));
typedef __bf16 bf16x4 __attribute__((ext_vector_type(4)));
typedef float f32x4 __attribute__((ext_vector_type(4)));
typedef unsigned int u32x4 __attribute__((ext_vector_type(4)));

#define LOG2E 1.44269504088896f

__device__ __forceinline__ bf16x8 cvt8(const float* __restrict__ p) {
    f32x4 a = *(const f32x4*)p;
    f32x4 b = *(const f32x4*)(p + 4);
    bf16x8 o;
    o[0] = (__bf16)a[0]; o[1] = (__bf16)a[1]; o[2] = (__bf16)a[2]; o[3] = (__bf16)a[3];
    o[4] = (__bf16)b[0]; o[5] = (__bf16)b[1]; o[6] = (__bf16)b[2]; o[7] = (__bf16)b[3];
    return o;
}

__device__ __forceinline__ void gll16(const __bf16* g, __bf16* l) {
    __builtin_amdgcn_global_load_lds(
        (const __attribute__((address_space(1))) void*)g,
        (__attribute__((address_space(3))) void*)l, 16, 0, 0);
}

__device__ __forceinline__ uint32_t packbf(__bf16 lo, __bf16 hi) {
    uint16_t a = __builtin_bit_cast(uint16_t, lo);
    uint16_t b = __builtin_bit_cast(uint16_t, hi);
    return (uint32_t)a | ((uint32_t)b << 16);
}
__device__ __forceinline__ float lo2f(uint32_t u) { return __builtin_bit_cast(float, u << 16); }
__device__ __forceinline__ float hi2f(uint32_t u) { return __builtin_bit_cast(float, u & 0xffff0000u); }

template<int CTRL>
__device__ __forceinline__ float qp_add(float v) {
    int r = __builtin_amdgcn_update_dpp(0, __builtin_bit_cast(int, v), CTRL, 0xF, 0xF, true);
    return v + __builtin_bit_cast(float, r);
}

// ---------------------------------------------------------------------------
// fused f32->bf16 convert: u | W_in | W_out | W_x | W_dt (8 elems/thread)
// ---------------------------------------------------------------------------
__global__ void cvt_all_kernel(const float* __restrict__ u,   __bf16* __restrict__ ub,
                               const float* __restrict__ wi,  __bf16* __restrict__ wib,
                               const float* __restrict__ wo,  __bf16* __restrict__ wob,
                               const float* __restrict__ wx,  __bf16* __restrict__ wxb,
                               const float* __restrict__ wdt, __bf16* __restrict__ wdtb) {
    int i = blockIdx.x * 256 + threadIdx.x;      // 0 .. 1351679
    const float* s; __bf16* d; int off;
    if (i < 524288)                { s = u;   d = ub;   off = i; }
    else if (i < 1048576)          { s = wi;  d = wib;  off = i - 524288; }
    else if (i < 1310720)          { s = wo;  d = wob;  off = i - 1048576; }
    else if (i < 1335296)          { s = wx;  d = wxb;  off = i - 1310720; }
    else                           { s = wdt; d = wdtb; off = i - 1335296; }
    *(bf16x8*)(d + (size_t)off * 8) = cvt8(s + (size_t)off * 8);
}

// ---------------------------------------------------------------------------
// m97-style GEMM: C_bf16[M][ldc] = A[M][K] @ B[N][K]^T (bf16 in)
// ---------------------------------------------------------------------------
__global__ __launch_bounds__(256, 3) void gemm_async_bf(const __bf16* __restrict__ A,
                                                        const __bf16* __restrict__ Bw,
                                                        __bf16* __restrict__ C,
                                                        int K, int ldc) {
    __shared__ __bf16 As[128][32];
    __shared__ __bf16 Bs[128][32];
    const int tid = threadIdx.x, lane = tid & 63, wave = tid >> 6;
    const int m0 = blockIdx.x * 128, n0 = blockIdx.y * 128;
    const int wm = (wave >> 1) * 64, wn = (wave & 1) * 64;
    const int mrow = lane & 15, kq = (lane >> 4) * 8;
    const int sr = wave * 32 + (lane >> 2);
    const int sk = (lane & 3) * 8;
    const __bf16* Ag0 = A + (size_t)(m0 + sr) * K + sk;
    const __bf16* Ag1 = Ag0 + (size_t)16 * K;
    const __bf16* Bg0 = Bw + (size_t)(n0 + sr) * K + sk;
    const __bf16* Bg1 = Bg0 + (size_t)16 * K;
    __bf16* La0 = &As[wave * 32][0];
    __bf16* La1 = &As[wave * 32 + 16][0];
    __bf16* Lb0 = &Bs[wave * 32][0];
    __bf16* Lb1 = &Bs[wave * 32 + 16][0];
    f32x4 acc[4][4] = {};
    for (int k0 = 0; k0 < K; k0 += 32) {
        gll16(Ag0 + k0, La0);
        gll16(Ag1 + k0, La1);
        gll16(Bg0 + k0, Lb0);
        gll16(Bg1 + k0, Lb1);
        __syncthreads();
        bf16x8 af[4], bfr[4];
#pragma unroll
        for (int i = 0; i < 4; ++i) af[i]  = *(const bf16x8*)&As[wm + i * 16 + mrow][kq];
#pragma unroll
        for (int j = 0; j < 4; ++j) bfr[j] = *(const bf16x8*)&Bs[wn + j * 16 + mrow][kq];
#pragma unroll
        for (int i = 0; i < 4; ++i)
#pragma unroll
            for (int j = 0; j < 4; ++j)
                acc[i][j] = __builtin_amdgcn_mfma_f32_16x16x32_bf16(af[i], bfr[j], acc[i][j], 0, 0, 0);
        __syncthreads();
    }
    const int col = lane & 15;
    const int rb = (lane >> 4) * 4;
#pragma unroll
    for (int i = 0; i < 4; ++i)
#pragma unroll
        for (int j = 0; j < 4; ++j)
#pragma unroll
            for (int r = 0; r < 4; ++r)
                C[(size_t)(m0 + wm + i * 16 + rb + r) * ldc + n0 + wn + j * 16 + col] =
                    (__bf16)acc[i][j][r];
}

// ---------------------------------------------------------------------------
// gemm6 split-K: P[z][4096][1024] = A[:, z*1024:+1024] @ B[:, z*1024:+1024]^T
// A/B row stride 2048. grid (32, 8, 2).
// ---------------------------------------------------------------------------
__global__ __launch_bounds__(256, 3) void gemm_splitk(const __bf16* __restrict__ A,
                                                      const __bf16* __restrict__ Bw,
                                                      float* __restrict__ P) {
    __shared__ __bf16 As[128][32];
    __shared__ __bf16 Bs[128][32];
    const int tid = threadIdx.x, lane = tid & 63, wave = tid >> 6;
    const int m0 = blockIdx.x * 128, n0 = blockIdx.y * 128;
    const int kz = blockIdx.z * 1024;
    const int wm = (wave >> 1) * 64, wn = (wave & 1) * 64;
    const int mrow = lane & 15, kq = (lane >> 4) * 8;
    const int sr = wave * 32 + (lane >> 2);
    const int sk = (lane & 3) * 8;
    const __bf16* Ag0 = A + (size_t)(m0 + sr) * 2048 + kz + sk;
    const __bf16* Ag1 = Ag0 + (size_t)16 * 2048;
    const __bf16* Bg0 = Bw + (size_t)(n0 + sr) * 2048 + kz + sk;
    const __bf16* Bg1 = Bg0 + (size_t)16 * 2048;
    __bf16* La0 = &As[wave * 32][0];
    __bf16* La1 = &As[wave * 32 + 16][0];
    __bf16* Lb0 = &Bs[wave * 32][0];
    __bf16* Lb1 = &Bs[wave * 32 + 16][0];
    f32x4 acc[4][4] = {};
    for (int k0 = 0; k0 < 1024; k0 += 32) {
        gll16(Ag0 + k0, La0);
        gll16(Ag1 + k0, La1);
        gll16(Bg0 + k0, Lb0);
        gll16(Bg1 + k0, Lb1);
        __syncthreads();
        bf16x8 af[4], bfr[4];
#pragma unroll
        for (int i = 0; i < 4; ++i) af[i]  = *(const bf16x8*)&As[wm + i * 16 + mrow][kq];
#pragma unroll
        for (int j = 0; j < 4; ++j) bfr[j] = *(const bf16x8*)&Bs[wn + j * 16 + mrow][kq];
#pragma unroll
        for (int i = 0; i < 4; ++i)
#pragma unroll
            for (int j = 0; j < 4; ++j)
                acc[i][j] = __builtin_amdgcn_mfma_f32_16x16x32_bf16(af[i], bfr[j], acc[i][j], 0, 0, 0);
        __syncthreads();
    }
    const int col = lane & 15;
    const int rb = (lane >> 4) * 4;
    float* Pz = P + (size_t)blockIdx.z * 4096 * 1024;
#pragma unroll
    for (int i = 0; i < 4; ++i)
#pragma unroll
        for (int j = 0; j < 4; ++j)
#pragma unroll
            for (int r = 0; r < 4; ++r)
                Pz[(size_t)(m0 + wm + i * 16 + rb + r) * 1024 + n0 + wn + j * 16 + col] =
                    acc[i][j][r];
}

// out = P0 + P1, 4.19M f32, f32x4 per thread
__global__ void add2_kernel(const float* __restrict__ P, float* __restrict__ out) {
    int i = blockIdx.x * 256 + threadIdx.x;       // 0..1048575
    f32x4 a = *(const f32x4*)(P + (size_t)i * 4);
    f32x4 b = *(const f32x4*)(P + (size_t)4096 * 1024 + (size_t)i * 4);
    *(f32x4*)(out + (size_t)i * 4) = a + b;
}

// ---------------------------------------------------------------------------
// Causal depthwise conv (K=4) + SiLU
// ---------------------------------------------------------------------------
__global__ void conv_silu_kernel(const __bf16* __restrict__ xz,
                                 const float* __restrict__ cw,
                                 const float* __restrict__ cb,
                                 __bf16* __restrict__ x) {
    int tid = threadIdx.x;
    int r = blockIdx.x;
    int l = r & 2047;
    int d = tid * 8;

    float acc[8];
#pragma unroll
    for (int i = 0; i < 8; ++i) acc[i] = cb[d + i];

#pragma unroll
    for (int dlt = 0; dlt < 4; ++dlt) {
        if (l - dlt < 0) break;
        bf16x8 v = *(const bf16x8*)(xz + (size_t)(r - dlt) * 4096 + d);
#pragma unroll
        for (int i = 0; i < 8; ++i)
            acc[i] += (float)v[i] * cw[(d + i) * 4 + 3 - dlt];
    }
    bf16x8 o;
#pragma unroll
    for (int i = 0; i < 8; ++i) {
        float s = acc[i];
        s = s / (1.f + __expf(-s));
        o[i] = (__bf16)s;
    }
    *(bf16x8*)(x + (size_t)r * 2048 + d) = o;
}

// ---------------------------------------------------------------------------
// gemm_xp split-K: P[ks][4096][96] = x[:, ks*256:+256] @ Wx^T
// ---------------------------------------------------------------------------
__global__ __launch_bounds__(256, 2) void gemm_xp_split(const __bf16* __restrict__ A,
                                                        const __bf16* __restrict__ Bw,
                                                        float* __restrict__ P) {
    __shared__ __bf16 As[64][64];
    __shared__ __bf16 Bs[96][64];
    const int tid = threadIdx.x;
    const int lane = tid & 63;
    const int wave = tid >> 6;
    const int m0 = blockIdx.x * 64;
    const int kb = blockIdx.y * 256;
    const int mrow = lane & 15;
    const int kq = (lane >> 4) * 8;

    f32x4 acc[6] = {};

    for (int k0 = kb; k0 < kb + 256; k0 += 64) {
#pragma unroll
        for (int r = 0; r < 2; ++r) {
            int e = r * 256 + tid;
            int row = e >> 3, kc = e & 7;
            *(bf16x8*)&As[row][kc * 8] =
                *(const bf16x8*)(A + (size_t)(m0 + row) * 2048 + k0 + kc * 8);
        }
#pragma unroll
        for (int r = 0; r < 3; ++r) {
            int e = r * 256 + tid;
            int row = e >> 3, kc = e & 7;
            *(bf16x8*)&Bs[row][kc * 8] =
                *(const bf16x8*)(Bw + (size_t)row * 2048 + k0 + kc * 8);
        }
        __syncthreads();
#pragma unroll
        for (int kc = 0; kc < 2; ++kc) {
            bf16x8 af = *(const bf16x8*)&As[wave * 16 + mrow][kc * 32 + kq];
#pragma unroll
            for (int j = 0; j < 6; ++j) {
                bf16x8 bfr = *(const bf16x8*)&Bs[j * 16 + mrow][kc * 32 + kq];
                acc[j] = __builtin_amdgcn_mfma_f32_16x16x32_bf16(af, bfr, acc[j], 0, 0, 0);
            }
        }
        __syncthreads();
    }
    const int col = lane & 15;
    const int rb = (lane >> 4) * 4;
    float* Pb = P + (size_t)blockIdx.y * 4096 * 96;
#pragma unroll
    for (int j = 0; j < 6; ++j)
#pragma unroll
        for (int r = 0; r < 4; ++r)
            Pb[(size_t)(m0 + wave * 16 + rb + r) * 96 + j * 16 + col] = acc[j][r];
}

__global__ void xp_reduce(const float* __restrict__ P, __bf16* __restrict__ xp) {
    int m = blockIdx.x, c = threadIdx.x;
    if (c < 96) {
        float s = 0.f;
#pragma unroll
        for (int k = 0; k < 8; ++k) s += P[(size_t)k * 4096 * 96 + (size_t)m * 96 + c];
        xp[(size_t)m * 96 + c] = (__bf16)s;
    }
}

// ---------------------------------------------------------------------------
// dt = softplus(x_p[:, :64] @ W_dt^T + b_dt) -> bf16 into xz[:, :2048]
// ---------------------------------------------------------------------------
__global__ __launch_bounds__(256, 2) void gemm_dt(const __bf16* __restrict__ xp,
                                                  const __bf16* __restrict__ Wdt,
                                                  const float* __restrict__ bdt,
                                                  __bf16* __restrict__ dt) {
    const int tid = threadIdx.x;
    const int lane = tid & 63;
    const int wave = tid >> 6;
    const int m0 = blockIdx.x * 128 + (wave >> 1) * 64;
    const int n0 = blockIdx.y * 128 + (wave & 1) * 64;
    const int mrow = lane & 15;
    const int kq = (lane >> 4) * 8;

    f32x4 acc[4][4] = {};
#pragma unroll
    for (int kc = 0; kc < 2; ++kc) {
        bf16x8 af[4], bfr[4];
#pragma unroll
        for (int i = 0; i < 4; ++i)
            af[i] = *(const bf16x8*)(xp + (size_t)(m0 + i * 16 + mrow) * 96 + kc * 32 + kq);
#pragma unroll
        for (int j = 0; j < 4; ++j)
            bfr[j] = *(const bf16x8*)(Wdt + (size_t)(n0 + j * 16 + mrow) * 64 + kc * 32 + kq);
#pragma unroll
        for (int i = 0; i < 4; ++i)
#pragma unroll
            for (int j = 0; j < 4; ++j)
                acc[i][j] = __builtin_amdgcn_mfma_f32_16x16x32_bf16(af[i], bfr[j], acc[i][j], 0, 0, 0);
    }
    const int col = lane & 15;
    const int rb = (lane >> 4) * 4;
#pragma unroll
    for (int i = 0; i < 4; ++i)
#pragma unroll
        for (int j = 0; j < 4; ++j) {
            int cc = n0 + j * 16 + col;
            float bias = bdt[cc];
#pragma unroll
            for (int r = 0; r < 4; ++r) {
                float v = acc[i][j][r] + bias;
                float sp = (v > 20.f) ? v : log1pf(__expf(v));
                dt[(size_t)(m0 + i * 16 + rb + r) * 4096 + cc] = (__bf16)sp;
            }
        }
}

// ---------------------------------------------------------------------------
// Chunked scan: 32 chunks x 64 steps. Block = 64 d x 4 waves; wave = 16 d x
// 4 n-groups, 4 states/thread. Grid = 2b x 32c x 32 dtiles = 2048 blocks.
// ---------------------------------------------------------------------------
__global__ __launch_bounds__(256, 6) void scan_p1(const __bf16* __restrict__ xz,
                                                  const __bf16* __restrict__ xq,
                                                  const __bf16* __restrict__ xp,
                                                  const float* __restrict__ A_log,
                                                  float* __restrict__ h_end,
                                                  float* __restrict__ dtsum) {
    __shared__ uint32_t s_dtx[64][64];    // (x<<16)|dt
    __shared__ __bf16 s_B[64][16];
    const int tid = threadIdx.x;
    const int bi = blockIdx.x;
    const int b = bi >> 10, c = (bi >> 5) & 31, d0 = (bi & 31) * 64;
    const int row0 = b * 2048 + c * 64;

    const int lane = tid & 63, wave = tid >> 6;
    const int dcol = wave * 16 + (lane >> 2);
    const int d = d0 + dcol;
    const int ng = lane & 3;
    f32x4 Al = *(const f32x4*)(A_log + (size_t)d * 16 + ng * 4);
    float Adn2[4];
#pragma unroll
    for (int j = 0; j < 4; ++j) Adn2[j] = -__expf(Al[j]) * LOG2E;

    {
        int t = tid >> 2, g = (tid & 3) * 4;
        *(bf16x4*)&s_B[t][g] = *(const bf16x4*)(xp + (size_t)(row0 + t) * 96 + 64 + g);
    }
#pragma unroll
    for (int i = 0; i < 4; ++i) {
        int w = i * 256 + tid;
        int t = w >> 4, g = (w & 15) * 4;
        size_t r = (size_t)(row0 + t);
        bf16x4 dt4 = *(const bf16x4*)(xz + r * 4096 + d0 + g);
        bf16x4 x4  = *(const bf16x4*)(xq + r * 2048 + d0 + g);
        u32x4 o;
#pragma unroll
        for (int k = 0; k < 4; ++k) o[k] = packbf(dt4[k], x4[k]);
        *(u32x4*)&s_dtx[t][g] = o;
    }
    __syncthreads();

    float h[4] = {0.f, 0.f, 0.f, 0.f};
    float ds = 0.f;
#pragma unroll 8
    for (int t = 0; t < 64; ++t) {
        uint32_t u = s_dtx[t][dcol];
        float dt = lo2f(u), x = hi2f(u);
        bf16x4 B4 = *(const bf16x4*)&s_B[t][ng * 4];
        float p = dt * x;
#pragma unroll
        for (int j = 0; j < 4; ++j) {
            float dA = exp2f(dt * Adn2[j]);
            h[j] = fmaf(dA, h[j], p * (float)B4[j]);
        }
        ds += dt;
    }
    size_t base = (size_t)(b * 32 + c) * 2048 + d;
    f32x4 hv = {h[0], h[1], h[2], h[3]};
    *(f32x4*)(h_end + base * 16 + ng * 4) = hv;
    if (ng == 0) dtsum[base] = ds;
}

// Phase 2: prefix over 32 chunks per (b,d,n). 65536 threads.
__global__ __launch_bounds__(256) void scan_p2(const float* __restrict__ A_log,
                                               const float* __restrict__ dtsum,
                                               const float* __restrict__ h_end,
                                               float* __restrict__ h_in) {
    int idx = blockIdx.x * 256 + threadIdx.x;
    int b = idx >> 15, rem = idx & 32767;
    int d = rem >> 4;
    float Adn = -__expf(A_log[rem]);
    float h = 0.f;
#pragma unroll
    for (int c = 0; c < 32; ++c) {
        size_t base = ((size_t)(b * 32 + c) << 15) + rem;
        h_in[base] = h;
        float P = __expf(Adn * dtsum[((size_t)(b * 32 + c) << 11) + d]);
        h = fmaf(P, h, h_end[base]);
    }
}

// Phase 3: rerun from h_in; y' = C.h + D*x to LDS; store applies silu(z).
__global__ __launch_bounds__(256, 4) void scan_p3(const __bf16* __restrict__ xz,
                                                  __bf16* __restrict__ xq,
                                                  const __bf16* __restrict__ xp,
                                                  const float* __restrict__ A_log,
                                                  const float* __restrict__ Dp,
                                                  const float* __restrict__ h_in) {
    __shared__ uint32_t s_dtx[64][64];    // (x<<16)|dt
    __shared__ uint32_t s_BC[64][16];     // (C<<16)|B
    __shared__ __bf16 s_y[64][64];        // raw y' = C.h + D*x
    const int tid = threadIdx.x;
    const int bi = blockIdx.x;
    const int b = bi >> 10, c = (bi >> 5) & 31, d0 = (bi & 31) * 64;
    const int row0 = b * 2048 + c * 64;

    const int lane = tid & 63, wave = tid >> 6;
    const int dcol = wave * 16 + (lane >> 2);
    const int d = d0 + dcol;
    const int ng = lane & 3;
    f32x4 Al = *(const f32x4*)(A_log + (size_t)d * 16 + ng * 4);
    float Adn2[4];
#pragma unroll
    for (int j = 0; j < 4; ++j) Adn2[j] = -__expf(Al[j]) * LOG2E;
    const float Dd = Dp[d];
    f32x4 h = *(const f32x4*)(h_in + ((size_t)(b * 32 + c) * 2048 + d) * 16 + ng * 4);

    {
        int t = tid >> 2, g = (tid & 3) * 4;
        bf16x4 B4 = *(const bf16x4*)(xp + (size_t)(row0 + t) * 96 + 64 + g);
        bf16x4 C4 = *(const bf16x4*)(xp + (size_t)(row0 + t) * 96 + 80 + g);
        u32x4 o;
#pragma unroll
        for (int k = 0; k < 4; ++k) o[k] = packbf(B4[k], C4[k]);
        *(u32x4*)&s_BC[t][g] = o;
    }
#pragma unroll
    for (int i = 0; i < 4; ++i) {
        int w = i * 256 + tid;
        int t = w >> 4, g = (w & 15) * 4;
        size_t r = (size_t)(row0 + t);
        bf16x4 dt4 = *(const bf16x4*)(xz + r * 4096 + d0 + g);
        bf16x4 x4  = *(const bf16x4*)(xq + r * 2048 + d0 + g);
        u32x4 o;
#pragma unroll
        for (int k = 0; k < 4; ++k) o[k] = packbf(dt4[k], x4[k]);
        *(u32x4*)&s_dtx[t][g] = o;
    }
    __syncthreads();

#pragma unroll 8
    for (int t = 0; t < 64; ++t) {
        uint32_t u = s_dtx[t][dcol];
        float dt = lo2f(u), x = hi2f(u);
        u32x4 bc = *(const u32x4*)&s_BC[t][ng * 4];
        float p = dt * x;
        float cs;
#pragma unroll
        for (int j = 0; j < 4; ++j) {
            float Bv = lo2f(bc[j]), Cv = hi2f(bc[j]);
            float dA = exp2f(dt * Adn2[j]);
            h[j] = fmaf(dA, h[j], p * Bv);
            cs = (j == 0) ? h[0] * Cv : fmaf(h[j], Cv, cs);
        }
        cs = qp_add<0xB1>(cs);
        cs = qp_add<0x4E>(cs);
        if (ng == 0) s_y[t][dcol] = (__bf16)fmaf(Dd, x, cs);
    }
    __syncthreads();
#pragma unroll
    for (int i = 0; i < 2; ++i) {
        int w = i * 256 + tid;
        int t = w >> 3, g = (w & 7) * 8;
        bf16x8 z8 = *(const bf16x8*)(xz + (size_t)(row0 + t) * 4096 + 2048 + d0 + g);
        bf16x8 y8 = *(bf16x8*)&s_y[t][g];
        bf16x8 o;
#pragma unroll
        for (int k = 0; k < 8; ++k) {
            float zv = (float)z8[k];
            float yv = (float)y8[k] * (zv / (1.f + __expf(-zv)));
            o[k] = (__bf16)yv;
        }
        *(bf16x8*)(xq + (size_t)(row0 + t) * 2048 + d0 + g) = o;
    }
}

// ---------------------------------------------------------------------------
extern "C" void kernel_launch(void* const* d_in, const int* in_sizes, int n_in,
                              void* d_out, int out_size, void* d_ws, size_t ws_size,
                              hipStream_t stream) {
    const float* u      = (const float*)d_in[0];
    const float* W_in   = (const float*)d_in[1];
    const float* W_out  = (const float*)d_in[2];
    const float* conv_w = (const float*)d_in[3];
    const float* conv_b = (const float*)d_in[4];
    const float* W_x    = (const float*)d_in[5];
    const float* W_dt   = (const float*)d_in[6];
    const float* b_dt   = (const float*)d_in[7];
    const float* A_log  = (const float*)d_in[8];
    const float* D_p    = (const float*)d_in[9];
    float* out = (float*)d_out;

    // ws (bf16), ~61.4 MB (unchanged from R5):
    __bf16* xz   = (__bf16*)d_ws;                   // [4096][4096]: x_in->dt | z; then gemm6 f32 partials
    __bf16* xq   = xz  + (size_t)4096 * 4096;       // [4096][2048]: x -> y
    __bf16* xp   = xq  + (size_t)4096 * 2048;       // [4096][96]
    __bf16* Wib  = xp  + (size_t)4096 * 96;         // W_in bf16; after gemm1: dtsum f32
    __bf16* Wob  = Wib + (size_t)4096 * 1024;       // W_out bf16 [1024][2048]
    __bf16* Wxb  = Wob + (size_t)1024 * 2048;       // W_x   bf16 [96][2048]
    __bf16* Wdtb = Wxb + (size_t)96 * 2048;         // W_dt  bf16 [2048][64]

    // d_out as scratch (16.78 MB), lifetimes disjoint:
    __bf16* ub    = (__bf16*)d_out;                 // u bf16 [0..8MB], dead after gemm1
    float* xpart  = (float*)d_out;                  // [8][4096][96] f32, dead after xp_reduce
    float* h_end  = (float*)d_out;                  // [64][2048][16] f32 [0..8.39MB], written in p1
    float* h_in   = (float*)d_out + 2097152;        // 8.39MB @ 8.39MB, written in p2
    float* dtsum  = (float*)Wib;                    // 512 KB in dead Wib region
    float* gpart  = (float*)xz;                     // [2][4096][1024] f32 = 33.55MB, after p3

    cvt_all_kernel<<<5280, 256, 0, stream>>>(u, ub, W_in, Wib, W_out, Wob,
                                             W_x, Wxb, W_dt, Wdtb);

    // 1. xz = ub @ Wib^T  (M=4096,N=4096,K=1024)
    gemm_async_bf<<<dim3(32, 32), 256, 0, stream>>>(ub, Wib, xz, 1024, 4096);
    // 2. x = silu(conv(x_in))
    conv_silu_kernel<<<4096, 256, 0, stream>>>(xz, conv_w, conv_b, xq);
    // 3. x_p split-K + reduce
    gemm_xp_split<<<dim3(64, 8), 256, 0, stream>>>(xq, Wxb, xpart);
    xp_reduce<<<4096, 128, 0, stream>>>(xpart, xp);
    // 4. dt -> xz[:, :2048]
    gemm_dt<<<dim3(32, 16), 256, 0, stream>>>(xp, Wdtb, b_dt, xz);
    // 5. chunked scan (32 x 64)
    scan_p1<<<2048, 256, 0, stream>>>(xz, xq, xp, A_log, h_end, dtsum);
    scan_p2<<<256, 256, 0, stream>>>(A_log, dtsum, h_end, h_in);
    scan_p3<<<2048, 256, 0, stream>>>(xz, xq, xp, A_log, D_p, h_in);
    // 6. out = y @ Wob^T split-K x2 (partials into dead xz) + reduce
    gemm_splitk<<<dim3(32, 8, 2), 256, 0, stream>>>(xq, Wob, gpart);
    add2_kernel<<<4096, 256, 0, stream>>>(gpart, out);
}

// Round 7
// 333.800 us; speedup vs baseline: 1.1776x; 1.1427x over previous
//
#include <hip/hip_runtime.h>
#include <hip/hip_bf16.h>
#include <cstdint>
#include <cstddef>

// B=2, L=2048, D_MODEL=1024, D_INNER=2048, D_STATE=16, D_CONV=4, DT_RANK=64
// M = B*L = 4096. All inputs/output fp32; internals bf16.
// R7: conv weight transpose (cwT[4][2048] f32) -> coalesced weight loads.
//     R6 conv was addr-divergence bound: 40 scalar loads/thread, 64 cache
//     lines per wave instruction (VALU 7%, HBM 10%, 63.9us).

typedef __bf16 bf16x8 __attribute__((ext_vector_type(8)));
typedef __bf16 bf16x4 __attribute__((ext_vector_type(4)));
typedef float f32x4 __attribute__((ext_vector_type(4)));
typedef unsigned int u32x4 __attribute__((ext_vector_type(4)));

#define LOG2E 1.44269504088896f

__device__ __forceinline__ bf16x8 cvt8(const float* __restrict__ p) {
    f32x4 a = *(const f32x4*)p;
    f32x4 b = *(const f32x4*)(p + 4);
    bf16x8 o;
    o[0] = (__bf16)a[0]; o[1] = (__bf16)a[1]; o[2] = (__bf16)a[2]; o[3] = (__bf16)a[3];
    o[4] = (__bf16)b[0]; o[5] = (__bf16)b[1]; o[6] = (__bf16)b[2]; o[7] = (__bf16)b[3];
    return o;
}

__device__ __forceinline__ void gll16(const __bf16* g, __bf16* l) {
    __builtin_amdgcn_global_load_lds(
        (const __attribute__((address_space(1))) void*)g,
        (__attribute__((address_space(3))) void*)l, 16, 0, 0);
}

__device__ __forceinline__ uint32_t packbf(__bf16 lo, __bf16 hi) {
    uint16_t a = __builtin_bit_cast(uint16_t, lo);
    uint16_t b = __builtin_bit_cast(uint16_t, hi);
    return (uint32_t)a | ((uint32_t)b << 16);
}
__device__ __forceinline__ float lo2f(uint32_t u) { return __builtin_bit_cast(float, u << 16); }
__device__ __forceinline__ float hi2f(uint32_t u) { return __builtin_bit_cast(float, u & 0xffff0000u); }

template<int CTRL>
__device__ __forceinline__ float qp_add(float v) {
    int r = __builtin_amdgcn_update_dpp(0, __builtin_bit_cast(int, v), CTRL, 0xF, 0xF, true);
    return v + __builtin_bit_cast(float, r);
}

// ---------------------------------------------------------------------------
// fused f32->bf16 convert: u | W_in | W_out | W_x | W_dt, plus conv-weight
// transpose cwT[k][d] = conv_w[d][k] (f32, coalesced consumer layout).
// ranges (8-elem units): u 524288 | W_in 524288 | W_out 262144 | W_x 24576 |
// W_dt 16384 | cwT 1024.  total 1352704 = 5284 * 256.
// ---------------------------------------------------------------------------
__global__ void cvt_all_kernel(const float* __restrict__ u,   __bf16* __restrict__ ub,
                               const float* __restrict__ wi,  __bf16* __restrict__ wib,
                               const float* __restrict__ wo,  __bf16* __restrict__ wob,
                               const float* __restrict__ wx,  __bf16* __restrict__ wxb,
                               const float* __restrict__ wdt, __bf16* __restrict__ wdtb,
                               const float* __restrict__ cw,  float* __restrict__ cwT) {
    int i = blockIdx.x * 256 + threadIdx.x;      // 0 .. 1352703
    if (i < 1351680) {
        const float* s; __bf16* d; int off;
        if (i < 524288)                { s = u;   d = ub;   off = i; }
        else if (i < 1048576)          { s = wi;  d = wib;  off = i - 524288; }
        else if (i < 1310720)          { s = wo;  d = wob;  off = i - 1048576; }
        else if (i < 1335296)          { s = wx;  d = wxb;  off = i - 1310720; }
        else                           { s = wdt; d = wdtb; off = i - 1335296; }
        *(bf16x8*)(d + (size_t)off * 8) = cvt8(s + (size_t)off * 8);
    } else {
        int off = (i - 1351680) * 8;             // 8 source elems of conv_w
#pragma unroll
        for (int e = 0; e < 8; ++e) {
            int s = off + e;
            cwT[(s & 3) * 2048 + (s >> 2)] = cw[s];
        }
    }
}

// ---------------------------------------------------------------------------
// m97-style GEMM: C_bf16[M][ldc] = A[M][K] @ B[N][K]^T (bf16 in)
// ---------------------------------------------------------------------------
__global__ __launch_bounds__(256, 3) void gemm_async_bf(const __bf16* __restrict__ A,
                                                        const __bf16* __restrict__ Bw,
                                                        __bf16* __restrict__ C,
                                                        int K, int ldc) {
    __shared__ __bf16 As[128][32];
    __shared__ __bf16 Bs[128][32];
    const int tid = threadIdx.x, lane = tid & 63, wave = tid >> 6;
    const int m0 = blockIdx.x * 128, n0 = blockIdx.y * 128;
    const int wm = (wave >> 1) * 64, wn = (wave & 1) * 64;
    const int mrow = lane & 15, kq = (lane >> 4) * 8;
    const int sr = wave * 32 + (lane >> 2);
    const int sk = (lane & 3) * 8;
    const __bf16* Ag0 = A + (size_t)(m0 + sr) * K + sk;
    const __bf16* Ag1 = Ag0 + (size_t)16 * K;
    const __bf16* Bg0 = Bw + (size_t)(n0 + sr) * K + sk;
    const __bf16* Bg1 = Bg0 + (size_t)16 * K;
    __bf16* La0 = &As[wave * 32][0];
    __bf16* La1 = &As[wave * 32 + 16][0];
    __bf16* Lb0 = &Bs[wave * 32][0];
    __bf16* Lb1 = &Bs[wave * 32 + 16][0];
    f32x4 acc[4][4] = {};
    for (int k0 = 0; k0 < K; k0 += 32) {
        gll16(Ag0 + k0, La0);
        gll16(Ag1 + k0, La1);
        gll16(Bg0 + k0, Lb0);
        gll16(Bg1 + k0, Lb1);
        __syncthreads();
        bf16x8 af[4], bfr[4];
#pragma unroll
        for (int i = 0; i < 4; ++i) af[i]  = *(const bf16x8*)&As[wm + i * 16 + mrow][kq];
#pragma unroll
        for (int j = 0; j < 4; ++j) bfr[j] = *(const bf16x8*)&Bs[wn + j * 16 + mrow][kq];
#pragma unroll
        for (int i = 0; i < 4; ++i)
#pragma unroll
            for (int j = 0; j < 4; ++j)
                acc[i][j] = __builtin_amdgcn_mfma_f32_16x16x32_bf16(af[i], bfr[j], acc[i][j], 0, 0, 0);
        __syncthreads();
    }
    const int col = lane & 15;
    const int rb = (lane >> 4) * 4;
#pragma unroll
    for (int i = 0; i < 4; ++i)
#pragma unroll
        for (int j = 0; j < 4; ++j)
#pragma unroll
            for (int r = 0; r < 4; ++r)
                C[(size_t)(m0 + wm + i * 16 + rb + r) * ldc + n0 + wn + j * 16 + col] =
                    (__bf16)acc[i][j][r];
}

// ---------------------------------------------------------------------------
// gemm6 split-K: P[z][4096][1024] = A[:, z*1024:+1024] @ B[:, z*1024:+1024]^T
// A/B row stride 2048. grid (32, 8, 2).
// ---------------------------------------------------------------------------
__global__ __launch_bounds__(256, 3) void gemm_splitk(const __bf16* __restrict__ A,
                                                      const __bf16* __restrict__ Bw,
                                                      float* __restrict__ P) {
    __shared__ __bf16 As[128][32];
    __shared__ __bf16 Bs[128][32];
    const int tid = threadIdx.x, lane = tid & 63, wave = tid >> 6;
    const int m0 = blockIdx.x * 128, n0 = blockIdx.y * 128;
    const int kz = blockIdx.z * 1024;
    const int wm = (wave >> 1) * 64, wn = (wave & 1) * 64;
    const int mrow = lane & 15, kq = (lane >> 4) * 8;
    const int sr = wave * 32 + (lane >> 2);
    const int sk = (lane & 3) * 8;
    const __bf16* Ag0 = A + (size_t)(m0 + sr) * 2048 + kz + sk;
    const __bf16* Ag1 = Ag0 + (size_t)16 * 2048;
    const __bf16* Bg0 = Bw + (size_t)(n0 + sr) * 2048 + kz + sk;
    const __bf16* Bg1 = Bg0 + (size_t)16 * 2048;
    __bf16* La0 = &As[wave * 32][0];
    __bf16* La1 = &As[wave * 32 + 16][0];
    __bf16* Lb0 = &Bs[wave * 32][0];
    __bf16* Lb1 = &Bs[wave * 32 + 16][0];
    f32x4 acc[4][4] = {};
    for (int k0 = 0; k0 < 1024; k0 += 32) {
        gll16(Ag0 + k0, La0);
        gll16(Ag1 + k0, La1);
        gll16(Bg0 + k0, Lb0);
        gll16(Bg1 + k0, Lb1);
        __syncthreads();
        bf16x8 af[4], bfr[4];
#pragma unroll
        for (int i = 0; i < 4; ++i) af[i]  = *(const bf16x8*)&As[wm + i * 16 + mrow][kq];
#pragma unroll
        for (int j = 0; j < 4; ++j) bfr[j] = *(const bf16x8*)&Bs[wn + j * 16 + mrow][kq];
#pragma unroll
        for (int i = 0; i < 4; ++i)
#pragma unroll
            for (int j = 0; j < 4; ++j)
                acc[i][j] = __builtin_amdgcn_mfma_f32_16x16x32_bf16(af[i], bfr[j], acc[i][j], 0, 0, 0);
        __syncthreads();
    }
    const int col = lane & 15;
    const int rb = (lane >> 4) * 4;
    float* Pz = P + (size_t)blockIdx.z * 4096 * 1024;
#pragma unroll
    for (int i = 0; i < 4; ++i)
#pragma unroll
        for (int j = 0; j < 4; ++j)
#pragma unroll
            for (int r = 0; r < 4; ++r)
                Pz[(size_t)(m0 + wm + i * 16 + rb + r) * 1024 + n0 + wn + j * 16 + col] =
                    acc[i][j][r];
}

// out = P0 + P1, 4.19M f32, f32x4 per thread
__global__ void add2_kernel(const float* __restrict__ P, float* __restrict__ out) {
    int i = blockIdx.x * 256 + threadIdx.x;       // 0..1048575
    f32x4 a = *(const f32x4*)(P + (size_t)i * 4);
    f32x4 b = *(const f32x4*)(P + (size_t)4096 * 1024 + (size_t)i * 4);
    *(f32x4*)(out + (size_t)i * 4) = a + b;
}

// ---------------------------------------------------------------------------
// Causal depthwise conv (K=4) + SiLU.  Weights from transposed cwT[4][2048]
// (f32, lane-coalesced); bias f32; all loads 16B coalesced, taps predicated.
// ---------------------------------------------------------------------------
__global__ void conv_silu_kernel(const __bf16* __restrict__ xz,
                                 const float* __restrict__ cwT,
                                 const float* __restrict__ cb,
                                 __bf16* __restrict__ x) {
    int tid = threadIdx.x;
    int r = blockIdx.x;
    int l = r & 2047;
    int d = tid * 8;

    float acc[8];
    {
        f32x4 b0 = *(const f32x4*)(cb + d);
        f32x4 b1 = *(const f32x4*)(cb + d + 4);
#pragma unroll
        for (int i = 0; i < 4; ++i) { acc[i] = b0[i]; acc[4 + i] = b1[i]; }
    }

#pragma unroll
    for (int dlt = 0; dlt < 4; ++dlt) {     // y[l] += w[:,3-dlt] * x[l-dlt]
        if (l - dlt >= 0) {
            bf16x8 v = *(const bf16x8*)(xz + (size_t)(r - dlt) * 4096 + d);
            f32x4 w0 = *(const f32x4*)(cwT + (3 - dlt) * 2048 + d);
            f32x4 w1 = *(const f32x4*)(cwT + (3 - dlt) * 2048 + d + 4);
#pragma unroll
            for (int i = 0; i < 4; ++i) {
                acc[i]     = fmaf((float)v[i],     w0[i], acc[i]);
                acc[4 + i] = fmaf((float)v[4 + i], w1[i], acc[4 + i]);
            }
        }
    }
    bf16x8 o;
#pragma unroll
    for (int i = 0; i < 8; ++i) {
        float s = acc[i];
        s = s / (1.f + __expf(-s));
        o[i] = (__bf16)s;
    }
    *(bf16x8*)(x + (size_t)r * 2048 + d) = o;
}

// ---------------------------------------------------------------------------
// gemm_xp split-K: P[ks][4096][96] = x[:, ks*256:+256] @ Wx^T
// ---------------------------------------------------------------------------
__global__ __launch_bounds__(256, 2) void gemm_xp_split(const __bf16* __restrict__ A,
                                                        const __bf16* __restrict__ Bw,
                                                        float* __restrict__ P) {
    __shared__ __bf16 As[64][64];
    __shared__ __bf16 Bs[96][64];
    const int tid = threadIdx.x;
    const int lane = tid & 63;
    const int wave = tid >> 6;
    const int m0 = blockIdx.x * 64;
    const int kb = blockIdx.y * 256;
    const int mrow = lane & 15;
    const int kq = (lane >> 4) * 8;

    f32x4 acc[6] = {};

    for (int k0 = kb; k0 < kb + 256; k0 += 64) {
#pragma unroll
        for (int r = 0; r < 2; ++r) {
            int e = r * 256 + tid;
            int row = e >> 3, kc = e & 7;
            *(bf16x8*)&As[row][kc * 8] =
                *(const bf16x8*)(A + (size_t)(m0 + row) * 2048 + k0 + kc * 8);
        }
#pragma unroll
        for (int r = 0; r < 3; ++r) {
            int e = r * 256 + tid;
            int row = e >> 3, kc = e & 7;
            *(bf16x8*)&Bs[row][kc * 8] =
                *(const bf16x8*)(Bw + (size_t)row * 2048 + k0 + kc * 8);
        }
        __syncthreads();
#pragma unroll
        for (int kc = 0; kc < 2; ++kc) {
            bf16x8 af = *(const bf16x8*)&As[wave * 16 + mrow][kc * 32 + kq];
#pragma unroll
            for (int j = 0; j < 6; ++j) {
                bf16x8 bfr = *(const bf16x8*)&Bs[j * 16 + mrow][kc * 32 + kq];
                acc[j] = __builtin_amdgcn_mfma_f32_16x16x32_bf16(af, bfr, acc[j], 0, 0, 0);
            }
        }
        __syncthreads();
    }
    const int col = lane & 15;
    const int rb = (lane >> 4) * 4;
    float* Pb = P + (size_t)blockIdx.y * 4096 * 96;
#pragma unroll
    for (int j = 0; j < 6; ++j)
#pragma unroll
        for (int r = 0; r < 4; ++r)
            Pb[(size_t)(m0 + wave * 16 + rb + r) * 96 + j * 16 + col] = acc[j][r];
}

__global__ void xp_reduce(const float* __restrict__ P, __bf16* __restrict__ xp) {
    int m = blockIdx.x, c = threadIdx.x;
    if (c < 96) {
        float s = 0.f;
#pragma unroll
        for (int k = 0; k < 8; ++k) s += P[(size_t)k * 4096 * 96 + (size_t)m * 96 + c];
        xp[(size_t)m * 96 + c] = (__bf16)s;
    }
}

// ---------------------------------------------------------------------------
// dt = softplus(x_p[:, :64] @ W_dt^T + b_dt) -> bf16 into xz[:, :2048]
// ---------------------------------------------------------------------------
__global__ __launch_bounds__(256, 2) void gemm_dt(const __bf16* __restrict__ xp,
                                                  const __bf16* __restrict__ Wdt,
                                                  const float* __restrict__ bdt,
                                                  __bf16* __restrict__ dt) {
    const int tid = threadIdx.x;
    const int lane = tid & 63;
    const int wave = tid >> 6;
    const int m0 = blockIdx.x * 128 + (wave >> 1) * 64;
    const int n0 = blockIdx.y * 128 + (wave & 1) * 64;
    const int mrow = lane & 15;
    const int kq = (lane >> 4) * 8;

    f32x4 acc[4][4] = {};
#pragma unroll
    for (int kc = 0; kc < 2; ++kc) {
        bf16x8 af[4], bfr[4];
#pragma unroll
        for (int i = 0; i < 4; ++i)
            af[i] = *(const bf16x8*)(xp + (size_t)(m0 + i * 16 + mrow) * 96 + kc * 32 + kq);
#pragma unroll
        for (int j = 0; j < 4; ++j)
            bfr[j] = *(const bf16x8*)(Wdt + (size_t)(n0 + j * 16 + mrow) * 64 + kc * 32 + kq);
#pragma unroll
        for (int i = 0; i < 4; ++i)
#pragma unroll
            for (int j = 0; j < 4; ++j)
                acc[i][j] = __builtin_amdgcn_mfma_f32_16x16x32_bf16(af[i], bfr[j], acc[i][j], 0, 0, 0);
    }
    const int col = lane & 15;
    const int rb = (lane >> 4) * 4;
#pragma unroll
    for (int i = 0; i < 4; ++i)
#pragma unroll
        for (int j = 0; j < 4; ++j) {
            int cc = n0 + j * 16 + col;
            float bias = bdt[cc];
#pragma unroll
            for (int r = 0; r < 4; ++r) {
                float v = acc[i][j][r] + bias;
                float sp = (v > 20.f) ? v : log1pf(__expf(v));
                dt[(size_t)(m0 + i * 16 + rb + r) * 4096 + cc] = (__bf16)sp;
            }
        }
}

// ---------------------------------------------------------------------------
// Chunked scan: 32 chunks x 64 steps. Block = 64 d x 4 waves; wave = 16 d x
// 4 n-groups, 4 states/thread. Grid = 2b x 32c x 32 dtiles = 2048 blocks.
// ---------------------------------------------------------------------------
__global__ __launch_bounds__(256, 6) void scan_p1(const __bf16* __restrict__ xz,
                                                  const __bf16* __restrict__ xq,
                                                  const __bf16* __restrict__ xp,
                                                  const float* __restrict__ A_log,
                                                  float* __restrict__ h_end,
                                                  float* __restrict__ dtsum) {
    __shared__ uint32_t s_dtx[64][64];    // (x<<16)|dt
    __shared__ __bf16 s_B[64][16];
    const int tid = threadIdx.x;
    const int bi = blockIdx.x;
    const int b = bi >> 10, c = (bi >> 5) & 31, d0 = (bi & 31) * 64;
    const int row0 = b * 2048 + c * 64;

    const int lane = tid & 63, wave = tid >> 6;
    const int dcol = wave * 16 + (lane >> 2);
    const int d = d0 + dcol;
    const int ng = lane & 3;
    f32x4 Al = *(const f32x4*)(A_log + (size_t)d * 16 + ng * 4);
    float Adn2[4];
#pragma unroll
    for (int j = 0; j < 4; ++j) Adn2[j] = -__expf(Al[j]) * LOG2E;

    {
        int t = tid >> 2, g = (tid & 3) * 4;
        *(bf16x4*)&s_B[t][g] = *(const bf16x4*)(xp + (size_t)(row0 + t) * 96 + 64 + g);
    }
#pragma unroll
    for (int i = 0; i < 4; ++i) {
        int w = i * 256 + tid;
        int t = w >> 4, g = (w & 15) * 4;
        size_t r = (size_t)(row0 + t);
        bf16x4 dt4 = *(const bf16x4*)(xz + r * 4096 + d0 + g);
        bf16x4 x4  = *(const bf16x4*)(xq + r * 2048 + d0 + g);
        u32x4 o;
#pragma unroll
        for (int k = 0; k < 4; ++k) o[k] = packbf(dt4[k], x4[k]);
        *(u32x4*)&s_dtx[t][g] = o;
    }
    __syncthreads();

    float h[4] = {0.f, 0.f, 0.f, 0.f};
    float ds = 0.f;
#pragma unroll 8
    for (int t = 0; t < 64; ++t) {
        uint32_t u = s_dtx[t][dcol];
        float dt = lo2f(u), x = hi2f(u);
        bf16x4 B4 = *(const bf16x4*)&s_B[t][ng * 4];
        float p = dt * x;
#pragma unroll
        for (int j = 0; j < 4; ++j) {
            float dA = exp2f(dt * Adn2[j]);
            h[j] = fmaf(dA, h[j], p * (float)B4[j]);
        }
        ds += dt;
    }
    size_t base = (size_t)(b * 32 + c) * 2048 + d;
    f32x4 hv = {h[0], h[1], h[2], h[3]};
    *(f32x4*)(h_end + base * 16 + ng * 4) = hv;
    if (ng == 0) dtsum[base] = ds;
}

// Phase 2: prefix over 32 chunks per (b,d,n). 65536 threads.
__global__ __launch_bounds__(256) void scan_p2(const float* __restrict__ A_log,
                                               const float* __restrict__ dtsum,
                                               const float* __restrict__ h_end,
                                               float* __restrict__ h_in) {
    int idx = blockIdx.x * 256 + threadIdx.x;
    int b = idx >> 15, rem = idx & 32767;
    int d = rem >> 4;
    float Adn = -__expf(A_log[rem]);
    float h = 0.f;
#pragma unroll
    for (int c = 0; c < 32; ++c) {
        size_t base = ((size_t)(b * 32 + c) << 15) + rem;
        h_in[base] = h;
        float P = __expf(Adn * dtsum[((size_t)(b * 32 + c) << 11) + d]);
        h = fmaf(P, h, h_end[base]);
    }
}

// Phase 3: rerun from h_in; y' = C.h + D*x to LDS; store applies silu(z).
__global__ __launch_bounds__(256, 4) void scan_p3(const __bf16* __restrict__ xz,
                                                  __bf16* __restrict__ xq,
                                                  const __bf16* __restrict__ xp,
                                                  const float* __restrict__ A_log,
                                                  const float* __restrict__ Dp,
                                                  const float* __restrict__ h_in) {
    __shared__ uint32_t s_dtx[64][64];    // (x<<16)|dt
    __shared__ uint32_t s_BC[64][16];     // (C<<16)|B
    __shared__ __bf16 s_y[64][64];        // raw y' = C.h + D*x
    const int tid = threadIdx.x;
    const int bi = blockIdx.x;
    const int b = bi >> 10, c = (bi >> 5) & 31, d0 = (bi & 31) * 64;
    const int row0 = b * 2048 + c * 64;

    const int lane = tid & 63, wave = tid >> 6;
    const int dcol = wave * 16 + (lane >> 2);
    const int d = d0 + dcol;
    const int ng = lane & 3;
    f32x4 Al = *(const f32x4*)(A_log + (size_t)d * 16 + ng * 4);
    float Adn2[4];
#pragma unroll
    for (int j = 0; j < 4; ++j) Adn2[j] = -__expf(Al[j]) * LOG2E;
    const float Dd = Dp[d];
    f32x4 h = *(const f32x4*)(h_in + ((size_t)(b * 32 + c) * 2048 + d) * 16 + ng * 4);

    {
        int t = tid >> 2, g = (tid & 3) * 4;
        bf16x4 B4 = *(const bf16x4*)(xp + (size_t)(row0 + t) * 96 + 64 + g);
        bf16x4 C4 = *(const bf16x4*)(xp + (size_t)(row0 + t) * 96 + 80 + g);
        u32x4 o;
#pragma unroll
        for (int k = 0; k < 4; ++k) o[k] = packbf(B4[k], C4[k]);
        *(u32x4*)&s_BC[t][g] = o;
    }
#pragma unroll
    for (int i = 0; i < 4; ++i) {
        int w = i * 256 + tid;
        int t = w >> 4, g = (w & 15) * 4;
        size_t r = (size_t)(row0 + t);
        bf16x4 dt4 = *(const bf16x4*)(xz + r * 4096 + d0 + g);
        bf16x4 x4  = *(const bf16x4*)(xq + r * 2048 + d0 + g);
        u32x4 o;
#pragma unroll
        for (int k = 0; k < 4; ++k) o[k] = packbf(dt4[k], x4[k]);
        *(u32x4*)&s_dtx[t][g] = o;
    }
    __syncthreads();

#pragma unroll 8
    for (int t = 0; t < 64; ++t) {
        uint32_t u = s_dtx[t][dcol];
        float dt = lo2f(u), x = hi2f(u);
        u32x4 bc = *(const u32x4*)&s_BC[t][ng * 4];
        float p = dt * x;
        float cs;
#pragma unroll
        for (int j = 0; j < 4; ++j) {
            float Bv = lo2f(bc[j]), Cv = hi2f(bc[j]);
            float dA = exp2f(dt * Adn2[j]);
            h[j] = fmaf(dA, h[j], p * Bv);
            cs = (j == 0) ? h[0] * Cv : fmaf(h[j], Cv, cs);
        }
        cs = qp_add<0xB1>(cs);
        cs = qp_add<0x4E>(cs);
        if (ng == 0) s_y[t][dcol] = (__bf16)fmaf(Dd, x, cs);
    }
    __syncthreads();
#pragma unroll
    for (int i = 0; i < 2; ++i) {
        int w = i * 256 + tid;
        int t = w >> 3, g = (w & 7) * 8;
        bf16x8 z8 = *(const bf16x8*)(xz + (size_t)(row0 + t) * 4096 + 2048 + d0 + g);
        bf16x8 y8 = *(bf16x8*)&s_y[t][g];
        bf16x8 o;
#pragma unroll
        for (int k = 0; k < 8; ++k) {
            float zv = (float)z8[k];
            float yv = (float)y8[k] * (zv / (1.f + __expf(-zv)));
            o[k] = (__bf16)yv;
        }
        *(bf16x8*)(xq + (size_t)(row0 + t) * 2048 + d0 + g) = o;
    }
}

// ---------------------------------------------------------------------------
extern "C" void kernel_launch(void* const* d_in, const int* in_sizes, int n_in,
                              void* d_out, int out_size, void* d_ws, size_t ws_size,
                              hipStream_t stream) {
    const float* u      = (const float*)d_in[0];
    const float* W_in   = (const float*)d_in[1];
    const float* W_out  = (const float*)d_in[2];
    const float* conv_w = (const float*)d_in[3];
    const float* conv_b = (const float*)d_in[4];
    const float* W_x    = (const float*)d_in[5];
    const float* W_dt   = (const float*)d_in[6];
    const float* b_dt   = (const float*)d_in[7];
    const float* A_log  = (const float*)d_in[8];
    const float* D_p    = (const float*)d_in[9];
    float* out = (float*)d_out;

    // ws (bf16), ~61.4 MB:
    __bf16* xz   = (__bf16*)d_ws;                   // [4096][4096]: x_in->dt | z; then gemm6 f32 partials
    __bf16* xq   = xz  + (size_t)4096 * 4096;       // [4096][2048]: x -> y
    __bf16* xp   = xq  + (size_t)4096 * 2048;       // [4096][96]
    __bf16* Wib  = xp  + (size_t)4096 * 96;         // W_in bf16; after gemm1: dtsum f32
    __bf16* Wob  = Wib + (size_t)4096 * 1024;       // W_out bf16 [1024][2048]
    __bf16* Wxb  = Wob + (size_t)1024 * 2048;       // W_x   bf16 [96][2048]
    __bf16* Wdtb = Wxb + (size_t)96 * 2048;         // W_dt  bf16 [2048][64]

    // d_out as scratch (16.78 MB), lifetimes disjoint:
    __bf16* ub    = (__bf16*)d_out;                 // u bf16 [0..8MB], dead after gemm1
    float* xpart  = (float*)d_out;                  // [8][4096][96] f32 [0..12.6MB], dead after xp_reduce
    float* h_end  = (float*)d_out;                  // [64][2048][16] f32 [0..8.39MB], written in p1
    float* h_in   = (float*)d_out + 2097152;        // 8.39MB @ 8.39MB, written in p2
    float* cwT    = (float*)d_out + 3407872;        // 32KB @ 13.63MB; live cvt->conv only
    float* dtsum  = (float*)Wib;                    // 512 KB in dead Wib region
    float* gpart  = (float*)xz;                     // [2][4096][1024] f32 = 33.55MB, after p3

    cvt_all_kernel<<<5284, 256, 0, stream>>>(u, ub, W_in, Wib, W_out, Wob,
                                             W_x, Wxb, W_dt, Wdtb, conv_w, cwT);

    // 1. xz = ub @ Wib^T  (M=4096,N=4096,K=1024)
    gemm_async_bf<<<dim3(32, 32), 256, 0, stream>>>(ub, Wib, xz, 1024, 4096);
    // 2. x = silu(conv(x_in))
    conv_silu_kernel<<<4096, 256, 0, stream>>>(xz, cwT, conv_b, xq);
    // 3. x_p split-K + reduce
    gemm_xp_split<<<dim3(64, 8), 256, 0, stream>>>(xq, Wxb, xpart);
    xp_reduce<<<4096, 128, 0, stream>>>(xpart, xp);
    // 4. dt -> xz[:, :2048]
    gemm_dt<<<dim3(32, 16), 256, 0, stream>>>(xp, Wdtb, b_dt, xz);
    // 5. chunked scan (32 x 64)
    scan_p1<<<2048, 256, 0, stream>>>(xz, xq, xp, A_log, h_end, dtsum);
    scan_p2<<<256, 256, 0, stream>>>(A_log, dtsum, h_end, h_in);
    scan_p3<<<2048, 256, 0, stream>>>(xz, xq, xp, A_log, D_p, h_in);
    // 6. out = y @ Wob^T split-K x2 (partials into dead xz) + reduce
    gemm_splitk<<<dim3(32, 8, 2), 256, 0, stream>>>(xq, Wob, gpart);
    add2_kernel<<<4096, 256, 0, stream>>>(gpart, out);
}